// Round 9
// baseline (28.461 us; speedup 1.0000x reference)
//
#include <hip/hip_runtime.h>
#include <math.h>

#define NJ 24
#define NV 6890
#define NB 128

// Ancestor chains (closest ancestor first), -1 padded. Max depth 8.
__constant__ int d_anc[NJ][8] = {
  {-1,-1,-1,-1,-1,-1,-1,-1},
  { 0,-1,-1,-1,-1,-1,-1,-1},
  { 0,-1,-1,-1,-1,-1,-1,-1},
  { 0,-1,-1,-1,-1,-1,-1,-1},
  { 1, 0,-1,-1,-1,-1,-1,-1},
  { 2, 0,-1,-1,-1,-1,-1,-1},
  { 3, 0,-1,-1,-1,-1,-1,-1},
  { 4, 1, 0,-1,-1,-1,-1,-1},
  { 5, 2, 0,-1,-1,-1,-1,-1},
  { 6, 3, 0,-1,-1,-1,-1,-1},
  { 7, 4, 1, 0,-1,-1,-1,-1},
  { 8, 5, 2, 0,-1,-1,-1,-1},
  { 9, 6, 3, 0,-1,-1,-1,-1},
  { 9, 6, 3, 0,-1,-1,-1,-1},
  { 9, 6, 3, 0,-1,-1,-1,-1},
  {12, 9, 6, 3, 0,-1,-1,-1},
  {13, 9, 6, 3, 0,-1,-1,-1},
  {14, 9, 6, 3, 0,-1,-1,-1},
  {16,13, 9, 6, 3, 0,-1,-1},
  {17,14, 9, 6, 3, 0,-1,-1},
  {18,16,13, 9, 6, 3, 0,-1},
  {19,17,14, 9, 6, 3, 0,-1},
  {20,18,16,13, 9, 6, 3, 0},
  {21,19,17,14, 9, 6, 3, 0}
};
__constant__ int d_par[NJ] = {-1,0,0,0,1,2,3,4,5,6,7,8,9,9,9,12,13,14,16,17,18,19,20,21};

// Kernel 1: per-batch Rodrigues + parallel ancestor-path chain + J-correction.
// Output layout TRANSPOSED: Gc_t[b][j][m], j=r*4+c (12 rows), m contiguous
// (24). {Gc_t[j][m], Gc_t[j][m+1]} is an aligned SGPR pair for pk_fma.
__global__ __launch_bounds__(64) void chain_kernel(const float* __restrict__ J,
                                                   const float* __restrict__ pose,
                                                   float* __restrict__ Gc) {
    int b = blockIdx.x;
    int tid = threadIdx.x;
    __shared__ float A[NJ][12];   // local [R|t] per joint

    if (tid < NJ) {
        int i = tid;
        const float* p = pose + ((size_t)b * NJ + i) * 3;
        float rx = p[0], ry = p[1], rz = p[2];
        float ex = rx + 1e-8f, ey = ry + 1e-8f, ez = rz + 1e-8f;
        float theta = sqrtf(ex * ex + ey * ey + ez * ez);
        float inv = 1.0f / theta;
        float hx = rx * inv, hy = ry * inv, hz = rz * inv;
        float c = cosf(theta * (float)M_PI);
        float s = sinf(theta);
        float oc = 1.0f - c;
        const float* jp = J + ((size_t)b * NJ + i) * 3;
        int par = d_par[i];
        float tx, ty, tz;
        if (par < 0) {
            tx = jp[0]; ty = jp[1]; tz = jp[2];
        } else {
            const float* jq = J + ((size_t)b * NJ + par) * 3;
            tx = jp[0] - jq[0]; ty = jp[1] - jq[1]; tz = jp[2] - jq[2];
        }
        A[i][0]  = c + oc * hx * hx;
        A[i][1]  = oc * hx * hy - s * hz;
        A[i][2]  = oc * hx * hz + s * hy;
        A[i][3]  = tx;
        A[i][4]  = oc * hy * hx + s * hz;
        A[i][5]  = c + oc * hy * hy;
        A[i][6]  = oc * hy * hz - s * hx;
        A[i][7]  = ty;
        A[i][8]  = oc * hz * hx - s * hy;
        A[i][9]  = oc * hz * hy + s * hx;
        A[i][10] = c + oc * hz * hz;
        A[i][11] = tz;
    }
    __syncthreads();

    if (tid < NJ) {
        int i = tid;
        float M[12];
        #pragma unroll
        for (int j = 0; j < 12; j++) M[j] = A[i][j];

        for (int k = 0; k < 8; k++) {
            int p = d_anc[i][k];
            if (p < 0) break;
            float P[12];
            #pragma unroll
            for (int j = 0; j < 12; j++) P[j] = A[p][j];
            float N[12];
            #pragma unroll
            for (int r = 0; r < 3; r++) {
                float p0 = P[r*4+0], p1 = P[r*4+1], p2 = P[r*4+2], p3 = P[r*4+3];
                N[r*4+0] = p0 * M[0] + p1 * M[4] + p2 * M[8];
                N[r*4+1] = p0 * M[1] + p1 * M[5] + p2 * M[9];
                N[r*4+2] = p0 * M[2] + p1 * M[6] + p2 * M[10];
                N[r*4+3] = p0 * M[3] + p1 * M[7] + p2 * M[11] + p3;
            }
            #pragma unroll
            for (int j = 0; j < 12; j++) M[j] = N[j];
        }

        const float* jp = J + ((size_t)b * NJ + i) * 3;
        float jx = jp[0], jy = jp[1], jz = jp[2];
        float* o = Gc + (size_t)b * 288;   // [12][24]
        #pragma unroll
        for (int r = 0; r < 3; r++) {
            float g0 = M[r*4+0], g1 = M[r*4+1], g2 = M[r*4+2], g3 = M[r*4+3];
            float corr = g0 * jx + g1 * jy + g2 * jz;
            o[(r*4+0)*24 + i] = g0;
            o[(r*4+1)*24 + i] = g1;
            o[(r*4+2)*24 + i] = g2;
            o[(r*4+3)*24 + i] = g3 - corr;
        }
    }
}

typedef __attribute__((ext_vector_type(16))) float fx16;
typedef __attribute__((ext_vector_type(2)))  float f2;

__device__ __forceinline__ f2 mkf2(float a, float b) { f2 r; r.x = a; r.y = b; return r; }

// e is a compile-time constant after unrolling; &15 keeps dead arms in range.
#define GPAIR(e) ((e) < 16 ? mkf2(gA[(e) & 15], gA[((e) + 1) & 15]) \
                : (e) < 32 ? mkf2(gB[((e) - 16) & 15], gB[((e) - 15) & 15]) \
                           : mkf2(gC[((e) - 32) & 15], gC[((e) - 31) & 15]))

#define WSTRIDE 26   // floats per LDS row: even (8B-align for b64), gcd(26,32)=2 -> <=4-way banks

// Kernel 2: per-vertex skinning, 1 vertex/thread.
// W is staged through LDS with COALESCED global loads: per block, the
// 256-vertex W region (6 KB) is read lane-contiguously (16 lines/instr
// instead of 64 lines/instr for the old per-vertex stride-96 float4 reads),
// then each thread pulls its 12 weight PAIRS via ds_read_b64 -- exactly the
// (w[2q], w[2q+1]) pairs the pk_fma blend consumes. Gc path unchanged:
// 18x s_load_dwordx16 SMEM + v_pk_fma_f32.
__global__ __launch_bounds__(256) void lbs_kernel(const float* __restrict__ V,
                                                  const float* __restrict__ W,
                                                  const float* __restrict__ Gc,
                                                  float* __restrict__ out) {
    const int b = blockIdx.y;
    const int tid = threadIdx.x;
    const int v0 = blockIdx.x * 256;
    const int n = v0 + tid;

    __shared__ float wlds[256 * WSTRIDE];   // 26624 B

    // Cooperative coalesced staging: 1536 float4 = 256 verts x 24 floats.
    // Last block of last batch stops 78 float4 short of the buffer end, and
    // overreads within earlier batches land in the next batch's rows (staged
    // but never consumed) -- no guard needed before the barrier.
    {
        const float4* __restrict__ wsrc =
            (const float4*)(W + ((size_t)b * NV + v0) * 24);
        #pragma unroll
        for (int k = 0; k < 6; k++) {
            const int idx = k * 256 + tid;       // float4 index within block region
            float4 v = wsrc[idx];
            const int row  = idx / 6;            // vertex within block
            const int col  = (idx % 6) * 4;      // float offset within row (even)
            f2* dst = (f2*)&wlds[row * WSTRIDE + col];
            dst[0] = mkf2(v.x, v.y);
            dst[1] = mkf2(v.z, v.w);
        }
    }
    __syncthreads();

    if (n >= NV) return;

    const float* gb = Gc + (size_t)b * 288;

    // 12 weight pairs straight from LDS (b64, <=4-way banks).
    const f2* __restrict__ wrow = (const f2*)&wlds[tid * WSTRIDE];
    f2 wpr[12];
    #pragma unroll
    for (int q = 0; q < 12; q++) wpr[q] = wrow[q];

    f2 T2[12];
    #pragma unroll
    for (int j = 0; j < 12; j++) T2[j] = mkf2(0.0f, 0.0f);

    #pragma unroll
    for (int c = 0; c < 6; c++) {
        // rows j=2c (offsets 0..23) and j=2c+1 (offsets 24..47) of Gc_t[b]
        fx16 gA, gB, gC;
        const float* p = gb + c * 48;
        asm volatile("s_load_dwordx16 %0, %3, 0x0\n\t"
                     "s_load_dwordx16 %1, %3, 0x40\n\t"
                     "s_load_dwordx16 %2, %3, 0x80\n\t"
                     "s_waitcnt lgkmcnt(0)"
                     : "=&s"(gA), "=&s"(gB), "=&s"(gC)
                     : "s"(p));

        f2 TA = T2[2 * c + 0];
        f2 TB = T2[2 * c + 1];
        #pragma unroll
        for (int q = 0; q < 12; q++) {
            f2 gpA = GPAIR(2 * q);
            f2 gpB = GPAIR(24 + 2 * q);
            asm("v_pk_fma_f32 %0, %1, %2, %0" : "+v"(TA) : "v"(wpr[q]), "s"(gpA));
            asm("v_pk_fma_f32 %0, %1, %2, %0" : "+v"(TB) : "v"(wpr[q]), "s"(gpB));
        }
        T2[2 * c + 0] = TA;
        T2[2 * c + 1] = TB;
    }

    float T[12];
    #pragma unroll
    for (int j = 0; j < 12; j++) T[j] = T2[j].x + T2[j].y;

    const float* vp = V + ((size_t)b * NV + n) * 3;
    float vx = vp[0], vy = vp[1], vz = vp[2];
    float* op = out + ((size_t)b * NV + n) * 3;
    op[0] = T[0] * vx + T[1] * vy + T[2]  * vz + T[3];
    op[1] = T[4] * vx + T[5] * vy + T[6]  * vz + T[7];
    op[2] = T[8] * vx + T[9] * vy + T[10] * vz + T[11];
}

extern "C" void kernel_launch(void* const* d_in, const int* in_sizes, int n_in,
                              void* d_out, int out_size, void* d_ws, size_t ws_size,
                              hipStream_t stream) {
    const float* V    = (const float*)d_in[0];
    const float* J    = (const float*)d_in[1];
    const float* pose = (const float*)d_in[2];
    const float* W    = (const float*)d_in[3];
    float* out = (float*)d_out;
    float* Gc  = (float*)d_ws;  // NB*288 floats = 147456 B

    chain_kernel<<<NB, 64, 0, stream>>>(J, pose, Gc);
    dim3 grid((NV + 255) / 256, NB);
    lbs_kernel<<<grid, 256, 0, stream>>>(V, W, Gc, out);
}

// Round 10
// 26.521 us; speedup vs baseline: 1.0731x; 1.0731x over previous
//
#include <hip/hip_runtime.h>
#include <math.h>
#include <string.h>

#define NJ 24
#define NV 6890
#define NB 128

// Ancestor chains (closest ancestor first), -1 padded. Max depth 8.
__constant__ int d_anc[NJ][8] = {
  {-1,-1,-1,-1,-1,-1,-1,-1},
  { 0,-1,-1,-1,-1,-1,-1,-1},
  { 0,-1,-1,-1,-1,-1,-1,-1},
  { 0,-1,-1,-1,-1,-1,-1,-1},
  { 1, 0,-1,-1,-1,-1,-1,-1},
  { 2, 0,-1,-1,-1,-1,-1,-1},
  { 3, 0,-1,-1,-1,-1,-1,-1},
  { 4, 1, 0,-1,-1,-1,-1,-1},
  { 5, 2, 0,-1,-1,-1,-1,-1},
  { 6, 3, 0,-1,-1,-1,-1,-1},
  { 7, 4, 1, 0,-1,-1,-1,-1},
  { 8, 5, 2, 0,-1,-1,-1,-1},
  { 9, 6, 3, 0,-1,-1,-1,-1},
  { 9, 6, 3, 0,-1,-1,-1,-1},
  { 9, 6, 3, 0,-1,-1,-1,-1},
  {12, 9, 6, 3, 0,-1,-1,-1},
  {13, 9, 6, 3, 0,-1,-1,-1},
  {14, 9, 6, 3, 0,-1,-1,-1},
  {16,13, 9, 6, 3, 0,-1,-1},
  {17,14, 9, 6, 3, 0,-1,-1},
  {18,16,13, 9, 6, 3, 0,-1},
  {19,17,14, 9, 6, 3, 0,-1},
  {20,18,16,13, 9, 6, 3, 0},
  {21,19,17,14, 9, 6, 3, 0}
};
__constant__ int d_par[NJ] = {-1,0,0,0,1,2,3,4,5,6,7,8,9,9,9,12,13,14,16,17,18,19,20,21};

// Kernel 1: per-batch Rodrigues + parallel ancestor-path chain + J-correction.
// Output layout UNTRANSPOSED: Gc[b][m][12] (3x4 row-major per joint) — this is
// exactly the B[k][n] matrix (k=joint, n=flat 3x4 element) the MFMA consumes.
__global__ __launch_bounds__(64) void chain_kernel(const float* __restrict__ J,
                                                   const float* __restrict__ pose,
                                                   float* __restrict__ Gc) {
    int b = blockIdx.x;
    int tid = threadIdx.x;
    __shared__ float A[NJ][12];   // local [R|t] per joint

    if (tid < NJ) {
        int i = tid;
        const float* p = pose + ((size_t)b * NJ + i) * 3;
        float rx = p[0], ry = p[1], rz = p[2];
        float ex = rx + 1e-8f, ey = ry + 1e-8f, ez = rz + 1e-8f;
        float theta = sqrtf(ex * ex + ey * ey + ez * ez);
        float inv = 1.0f / theta;
        float hx = rx * inv, hy = ry * inv, hz = rz * inv;
        float c = cosf(theta * (float)M_PI);
        float s = sinf(theta);
        float oc = 1.0f - c;
        const float* jp = J + ((size_t)b * NJ + i) * 3;
        int par = d_par[i];
        float tx, ty, tz;
        if (par < 0) {
            tx = jp[0]; ty = jp[1]; tz = jp[2];
        } else {
            const float* jq = J + ((size_t)b * NJ + par) * 3;
            tx = jp[0] - jq[0]; ty = jp[1] - jq[1]; tz = jp[2] - jq[2];
        }
        A[i][0]  = c + oc * hx * hx;
        A[i][1]  = oc * hx * hy - s * hz;
        A[i][2]  = oc * hx * hz + s * hy;
        A[i][3]  = tx;
        A[i][4]  = oc * hy * hx + s * hz;
        A[i][5]  = c + oc * hy * hy;
        A[i][6]  = oc * hy * hz - s * hx;
        A[i][7]  = ty;
        A[i][8]  = oc * hz * hx - s * hy;
        A[i][9]  = oc * hz * hy + s * hx;
        A[i][10] = c + oc * hz * hz;
        A[i][11] = tz;
    }
    __syncthreads();

    if (tid < NJ) {
        int i = tid;
        float M[12];
        #pragma unroll
        for (int j = 0; j < 12; j++) M[j] = A[i][j];

        for (int k = 0; k < 8; k++) {
            int p = d_anc[i][k];
            if (p < 0) break;
            float P[12];
            #pragma unroll
            for (int j = 0; j < 12; j++) P[j] = A[p][j];
            float N[12];
            #pragma unroll
            for (int r = 0; r < 3; r++) {
                float p0 = P[r*4+0], p1 = P[r*4+1], p2 = P[r*4+2], p3 = P[r*4+3];
                N[r*4+0] = p0 * M[0] + p1 * M[4] + p2 * M[8];
                N[r*4+1] = p0 * M[1] + p1 * M[5] + p2 * M[9];
                N[r*4+2] = p0 * M[2] + p1 * M[6] + p2 * M[10];
                N[r*4+3] = p0 * M[3] + p1 * M[7] + p2 * M[11] + p3;
            }
            #pragma unroll
            for (int j = 0; j < 12; j++) M[j] = N[j];
        }

        const float* jp = J + ((size_t)b * NJ + i) * 3;
        float jx = jp[0], jy = jp[1], jz = jp[2];
        float* o = Gc + ((size_t)b * NJ + i) * 12;
        #pragma unroll
        for (int r = 0; r < 3; r++) {
            float g0 = M[r*4+0], g1 = M[r*4+1], g2 = M[r*4+2], g3 = M[r*4+3];
            float corr = g0 * jx + g1 * jy + g2 * jz;
            o[r*4+0] = g0;
            o[r*4+1] = g1;
            o[r*4+2] = g2;
            o[r*4+3] = g3 - corr;
        }
    }
}

typedef __attribute__((ext_vector_type(8))) short bf16x8;
typedef __attribute__((ext_vector_type(4))) float f32x4;

__device__ __forceinline__ short f2bf(float f) {
    unsigned int u;
    memcpy(&u, &f, 4);
    u += 0x7fffu + ((u >> 16) & 1u);   // round-to-nearest-even
    return (short)(u >> 16);
}

#define TLSTRIDE 20   // floats per scratch row: 80 B, 16B-aligned, conflict-free writes

// Kernel 2: skinning as a batched GEMM on the matrix cores.
// T[b] (6890x12) = W[b] (6890x24) @ Gc[b] (24x12), per 16-vert tile one
// mfma_f32_16x16x32_bf16 (K zero-padded 24->32, N 12->16). B-fragment (Gc)
// is loaded ONCE per wave (4 VGPRs) — no per-vertex Gc traffic, no serialized
// SMEM waits. A = W rows, aligned float4 pairs, cvt to bf16 in-flight.
// Epilogue: C fragments transposed through per-wave LDS scratch, then
// out = T(3x4) applied to [V,1]. No __syncthreads anywhere (wave-local LDS).
__global__ __launch_bounds__(256) void lbs_kernel(const float* __restrict__ V,
                                                  const float* __restrict__ W,
                                                  const float* __restrict__ Gc,
                                                  float* __restrict__ out) {
    const int b    = blockIdx.y;
    const int wave = threadIdx.x >> 6;
    const int lane = threadIdx.x & 63;
    const int vwave = blockIdx.x * 1024 + wave * 256;   // 256 verts per wave
    if (vwave >= NV) return;

    __shared__ float tl[4 * 64 * TLSTRIDE];   // 4 waves x 64 verts x 20 = 20480 B
    float* mytl = &tl[wave * 64 * TLSTRIDE];

    const int n16 = lane & 15;   // A: vertex slot | B: out-element n | C: col
    const int g   = lane >> 4;   // k-group (8 joints per group)

    // B fragment: B[k][n] = Gc[b][joint k][elem n], k = 8g + j; zero-pad
    // k>=24 and n>=12.
    const float* gb = Gc + (size_t)b * (NJ * 12);
    bf16x8 bfrag;
    #pragma unroll
    for (int j = 0; j < 8; j++) {
        const int k = 8 * g + j;
        const float gval = (k < NJ && n16 < 12) ? gb[k * 12 + n16] : 0.0f;
        bfrag[j] = f2bf(gval);
    }

    #pragma unroll 1
    for (int grp = 0; grp < 4; grp++) {
        const int gbase = vwave + grp * 64;

        #pragma unroll
        for (int t = 0; t < 4; t++) {
            const int tb = gbase + t * 16;
            const int v  = tb + n16;
            const int vc = v < NV ? v : NV - 1;

            // A fragment: W[vert v][k=8g..8g+7] as two aligned float4 (g<3).
            f32x4 lo = {0.f, 0.f, 0.f, 0.f}, hi = {0.f, 0.f, 0.f, 0.f};
            if (g < 3) {
                const float4* wp =
                    (const float4*)(W + ((size_t)b * NV + vc) * 24 + g * 8);
                float4 l4 = wp[0];
                float4 h4 = wp[1];
                lo[0] = l4.x; lo[1] = l4.y; lo[2] = l4.z; lo[3] = l4.w;
                hi[0] = h4.x; hi[1] = h4.y; hi[2] = h4.z; hi[3] = h4.w;
            }
            bf16x8 afrag;
            #pragma unroll
            for (int j = 0; j < 4; j++) afrag[j]     = f2bf(lo[j]);
            #pragma unroll
            for (int j = 0; j < 4; j++) afrag[4 + j] = f2bf(hi[j]);

            f32x4 acc = {0.f, 0.f, 0.f, 0.f};
            acc = __builtin_amdgcn_mfma_f32_16x16x32_bf16(afrag, bfrag, acc, 0, 0, 0);

            // C: lane holds rows 4g+r (vertex within tile), col n16 (T elem).
            #pragma unroll
            for (int r = 0; r < 4; r++) {
                const int lv = t * 16 + 4 * g + r;   // local vert within group
                mytl[lv * TLSTRIDE + n16] = acc[r];
            }
        }

        // Wave-synchronous LDS RAW: compiler orders via lgkmcnt (same buffer);
        // no cross-wave sharing, so no barrier needed.
        __builtin_amdgcn_wave_barrier();

        // Epilogue: one vert per lane (64 verts of this group).
        const int gv  = gbase + lane;
        const int gvc = gv < NV ? gv : NV - 1;
        const float* row = &mytl[lane * TLSTRIDE];
        f32x4 t0 = *(const f32x4*)(row + 0);   // T[0..3]
        f32x4 t1 = *(const f32x4*)(row + 4);   // T[4..7]
        f32x4 t2 = *(const f32x4*)(row + 8);   // T[8..11]

        const float* vp = V + ((size_t)b * NV + gvc) * 3;
        const float vx = vp[0], vy = vp[1], vz = vp[2];
        if (gv < NV) {
            float* op = out + ((size_t)b * NV + gv) * 3;
            op[0] = t0[0] * vx + t0[1] * vy + t0[2] * vz + t0[3];
            op[1] = t1[0] * vx + t1[1] * vy + t1[2] * vz + t1[3];
            op[2] = t2[0] * vx + t2[1] * vy + t2[2] * vz + t2[3];
        }
        __builtin_amdgcn_wave_barrier();   // keep next group's writes after reads
    }
}

extern "C" void kernel_launch(void* const* d_in, const int* in_sizes, int n_in,
                              void* d_out, int out_size, void* d_ws, size_t ws_size,
                              hipStream_t stream) {
    const float* V    = (const float*)d_in[0];
    const float* J    = (const float*)d_in[1];
    const float* pose = (const float*)d_in[2];
    const float* W    = (const float*)d_in[3];
    float* out = (float*)d_out;
    float* Gc  = (float*)d_ws;  // NB*NJ*12 floats = 147456 B

    chain_kernel<<<NB, 64, 0, stream>>>(J, pose, Gc);
    dim3 grid((NV + 1023) / 1024, NB);
    lbs_kernel<<<grid, 256, 0, stream>>>(V, W, Gc, out);
}

// Round 11
// 24.409 us; speedup vs baseline: 1.1660x; 1.0865x over previous
//
#include <hip/hip_runtime.h>
#include <math.h>
#include <string.h>

#define NJ 24
#define NV 6890
#define NB 128

// Ancestor chains (closest ancestor first), -1 padded. Max depth 8.
__constant__ int d_anc[NJ][8] = {
  {-1,-1,-1,-1,-1,-1,-1,-1},
  { 0,-1,-1,-1,-1,-1,-1,-1},
  { 0,-1,-1,-1,-1,-1,-1,-1},
  { 0,-1,-1,-1,-1,-1,-1,-1},
  { 1, 0,-1,-1,-1,-1,-1,-1},
  { 2, 0,-1,-1,-1,-1,-1,-1},
  { 3, 0,-1,-1,-1,-1,-1,-1},
  { 4, 1, 0,-1,-1,-1,-1,-1},
  { 5, 2, 0,-1,-1,-1,-1,-1},
  { 6, 3, 0,-1,-1,-1,-1,-1},
  { 7, 4, 1, 0,-1,-1,-1,-1},
  { 8, 5, 2, 0,-1,-1,-1,-1},
  { 9, 6, 3, 0,-1,-1,-1,-1},
  { 9, 6, 3, 0,-1,-1,-1,-1},
  { 9, 6, 3, 0,-1,-1,-1,-1},
  {12, 9, 6, 3, 0,-1,-1,-1},
  {13, 9, 6, 3, 0,-1,-1,-1},
  {14, 9, 6, 3, 0,-1,-1,-1},
  {16,13, 9, 6, 3, 0,-1,-1},
  {17,14, 9, 6, 3, 0,-1,-1},
  {18,16,13, 9, 6, 3, 0,-1},
  {19,17,14, 9, 6, 3, 0,-1},
  {20,18,16,13, 9, 6, 3, 0},
  {21,19,17,14, 9, 6, 3, 0}
};
__constant__ int d_par[NJ] = {-1,0,0,0,1,2,3,4,5,6,7,8,9,9,9,12,13,14,16,17,18,19,20,21};

typedef __attribute__((ext_vector_type(8))) short bf16x8;
typedef __attribute__((ext_vector_type(4))) float f32x4;

__device__ __forceinline__ short f2bf(float f) {
    unsigned int u;
    memcpy(&u, &f, 4);
    u += 0x7fffu + ((u >> 16) & 1u);   // round-to-nearest-even
    return (short)(u >> 16);
}

#define TLSTRIDE 20   // floats per scratch row: 80 B, 16B-aligned

// FUSED kernel: per-block redundant chain (7 blocks/batch recompute the 24
// joint transforms -- ~500 cycles on one wave, hidden under the other waves'
// memory streams) followed by the R10 MFMA skinning. Removes the second
// graph launch and the chain->lbs dependency bubble.
// T[b] (6890x12) = W[b] (6890x24) @ Gc[b] (24x12) per 16-vert MFMA tile
// (K zero-padded 24->32, N 12->16); B-fragment read once per wave from LDS.
__global__ __launch_bounds__(256) void lbs_fused(const float* __restrict__ V,
                                                 const float* __restrict__ J,
                                                 const float* __restrict__ pose,
                                                 const float* __restrict__ W,
                                                 float* __restrict__ out) {
    const int b   = blockIdx.y;
    const int tid = threadIdx.x;

    __shared__ float A_lds[NJ][12];     // local [R|t] per joint
    __shared__ float Gc_lds[NJ * 12];   // corrected global transforms
    __shared__ float tl[4 * 64 * TLSTRIDE];   // epilogue transpose scratch

    // ---- Phase 0: chain (all threads reach both barriers) ----
    if (tid < NJ) {
        const int i = tid;
        const float* p = pose + ((size_t)b * NJ + i) * 3;
        float rx = p[0], ry = p[1], rz = p[2];
        float ex = rx + 1e-8f, ey = ry + 1e-8f, ez = rz + 1e-8f;
        float theta = sqrtf(ex * ex + ey * ey + ez * ez);
        float inv = 1.0f / theta;
        float hx = rx * inv, hy = ry * inv, hz = rz * inv;
        float c = cosf(theta * (float)M_PI);
        float s = sinf(theta);
        float oc = 1.0f - c;
        const float* jp = J + ((size_t)b * NJ + i) * 3;
        int par = d_par[i];
        float tx, ty, tz;
        if (par < 0) {
            tx = jp[0]; ty = jp[1]; tz = jp[2];
        } else {
            const float* jq = J + ((size_t)b * NJ + par) * 3;
            tx = jp[0] - jq[0]; ty = jp[1] - jq[1]; tz = jp[2] - jq[2];
        }
        A_lds[i][0]  = c + oc * hx * hx;
        A_lds[i][1]  = oc * hx * hy - s * hz;
        A_lds[i][2]  = oc * hx * hz + s * hy;
        A_lds[i][3]  = tx;
        A_lds[i][4]  = oc * hy * hx + s * hz;
        A_lds[i][5]  = c + oc * hy * hy;
        A_lds[i][6]  = oc * hy * hz - s * hx;
        A_lds[i][7]  = ty;
        A_lds[i][8]  = oc * hz * hx - s * hy;
        A_lds[i][9]  = oc * hz * hy + s * hx;
        A_lds[i][10] = c + oc * hz * hz;
        A_lds[i][11] = tz;
    }
    __syncthreads();

    if (tid < NJ) {
        const int i = tid;
        float M[12];
        #pragma unroll
        for (int j = 0; j < 12; j++) M[j] = A_lds[i][j];

        for (int k = 0; k < 8; k++) {
            int p = d_anc[i][k];
            if (p < 0) break;
            float P[12];
            #pragma unroll
            for (int j = 0; j < 12; j++) P[j] = A_lds[p][j];
            float N[12];
            #pragma unroll
            for (int r = 0; r < 3; r++) {
                float p0 = P[r*4+0], p1 = P[r*4+1], p2 = P[r*4+2], p3 = P[r*4+3];
                N[r*4+0] = p0 * M[0] + p1 * M[4] + p2 * M[8];
                N[r*4+1] = p0 * M[1] + p1 * M[5] + p2 * M[9];
                N[r*4+2] = p0 * M[2] + p1 * M[6] + p2 * M[10];
                N[r*4+3] = p0 * M[3] + p1 * M[7] + p2 * M[11] + p3;
            }
            #pragma unroll
            for (int j = 0; j < 12; j++) M[j] = N[j];
        }

        const float* jp = J + ((size_t)b * NJ + i) * 3;
        float jx = jp[0], jy = jp[1], jz = jp[2];
        #pragma unroll
        for (int r = 0; r < 3; r++) {
            float g0 = M[r*4+0], g1 = M[r*4+1], g2 = M[r*4+2], g3 = M[r*4+3];
            float corr = g0 * jx + g1 * jy + g2 * jz;
            Gc_lds[i*12 + r*4+0] = g0;
            Gc_lds[i*12 + r*4+1] = g1;
            Gc_lds[i*12 + r*4+2] = g2;
            Gc_lds[i*12 + r*4+3] = g3 - corr;
        }
    }
    __syncthreads();

    // ---- Phase 1: MFMA skinning (R10 structure, bfrag from LDS) ----
    const int wave  = tid >> 6;
    const int lane  = tid & 63;
    const int vwave = blockIdx.x * 1024 + wave * 256;   // 256 verts per wave
    if (vwave >= NV) return;

    float* mytl = &tl[wave * 64 * TLSTRIDE];

    const int n16 = lane & 15;   // A: vertex slot | B: out-element n | C: col
    const int g   = lane >> 4;   // k-group (8 joints per group)

    // B fragment: B[k][n] = Gc[joint k][elem n], k = 8g + j; zero-pad
    // k>=24 and n>=12. Read once per wave (8 ds_read per lane).
    bf16x8 bfrag;
    #pragma unroll
    for (int j = 0; j < 8; j++) {
        const int k = 8 * g + j;
        const float gval = (k < NJ && n16 < 12) ? Gc_lds[k * 12 + n16] : 0.0f;
        bfrag[j] = f2bf(gval);
    }

    #pragma unroll 1
    for (int grp = 0; grp < 4; grp++) {
        const int gbase = vwave + grp * 64;

        #pragma unroll
        for (int t = 0; t < 4; t++) {
            const int tb = gbase + t * 16;
            const int v  = tb + n16;
            const int vc = v < NV ? v : NV - 1;

            // A fragment: W[vert v][k=8g..8g+7] as two aligned float4 (g<3).
            f32x4 lo = {0.f, 0.f, 0.f, 0.f}, hi = {0.f, 0.f, 0.f, 0.f};
            if (g < 3) {
                const float4* wp =
                    (const float4*)(W + ((size_t)b * NV + vc) * 24 + g * 8);
                float4 l4 = wp[0];
                float4 h4 = wp[1];
                lo[0] = l4.x; lo[1] = l4.y; lo[2] = l4.z; lo[3] = l4.w;
                hi[0] = h4.x; hi[1] = h4.y; hi[2] = h4.z; hi[3] = h4.w;
            }
            bf16x8 afrag;
            #pragma unroll
            for (int j = 0; j < 4; j++) afrag[j]     = f2bf(lo[j]);
            #pragma unroll
            for (int j = 0; j < 4; j++) afrag[4 + j] = f2bf(hi[j]);

            f32x4 acc = {0.f, 0.f, 0.f, 0.f};
            acc = __builtin_amdgcn_mfma_f32_16x16x32_bf16(afrag, bfrag, acc, 0, 0, 0);

            // C: lane holds rows 4g+r (vertex within tile), col n16 (T elem).
            #pragma unroll
            for (int r = 0; r < 4; r++) {
                const int lv = t * 16 + 4 * g + r;   // local vert within group
                mytl[lv * TLSTRIDE + n16] = acc[r];
            }
        }

        // Wave-synchronous LDS RAW within one wave; no cross-wave sharing.
        __builtin_amdgcn_wave_barrier();

        // Epilogue: one vert per lane (64 verts of this group).
        const int gv  = gbase + lane;
        const int gvc = gv < NV ? gv : NV - 1;
        const float* row = &mytl[lane * TLSTRIDE];
        f32x4 t0 = *(const f32x4*)(row + 0);   // T[0..3]
        f32x4 t1 = *(const f32x4*)(row + 4);   // T[4..7]
        f32x4 t2 = *(const f32x4*)(row + 8);   // T[8..11]

        const float* vp = V + ((size_t)b * NV + gvc) * 3;
        const float vx = vp[0], vy = vp[1], vz = vp[2];
        if (gv < NV) {
            float* op = out + ((size_t)b * NV + gv) * 3;
            op[0] = t0[0] * vx + t0[1] * vy + t0[2] * vz + t0[3];
            op[1] = t1[0] * vx + t1[1] * vy + t1[2] * vz + t1[3];
            op[2] = t2[0] * vx + t2[1] * vy + t2[2] * vz + t2[3];
        }
        __builtin_amdgcn_wave_barrier();   // keep next group's writes after reads
    }
}

extern "C" void kernel_launch(void* const* d_in, const int* in_sizes, int n_in,
                              void* d_out, int out_size, void* d_ws, size_t ws_size,
                              hipStream_t stream) {
    const float* V    = (const float*)d_in[0];
    const float* J    = (const float*)d_in[1];
    const float* pose = (const float*)d_in[2];
    const float* W    = (const float*)d_in[3];
    float* out = (float*)d_out;

    dim3 grid((NV + 1023) / 1024, NB);
    lbs_fused<<<grid, 256, 0, stream>>>(V, J, pose, W, out);
}